// Round 2
// 196.673 us; speedup vs baseline: 1.0487x; 1.0487x over previous
//
#include <hip/hip_runtime.h>

// B=64, I=2048, D=8, O=32, K=16.
// e-layout is o-major: e = o*16 + k. A 64-e slice = 4 complete o's, so the
// reduce kernel can squash locally (512 blocks instead of 64), and
// out[b][o][k] is contiguous at e.
//
// pass grid: 512 blocks = (h = bx>>8: b-half) x (ch = bx&255: 8-i chunk).
// Thread map: wave w = i-slot (8 i/chunk); lane l: o = l&31, kk = l>>5 (k-half).
// Per-thread W = W[i][o][:][kk*8..+8] = 64 floats, register-resident (asm-pinned).
//
// LDS float4 indices are XOR-swizzled: swz(f4) = f4 ^ ((f4>>3)&7) (involution,
// key bits disjoint from toggled bits). Lane f4 = o*4+kk*2+c has only 2 varying
// low bits -> naive b128 access would be 16-way bank-grouped; the key (o bits
// 1..3) spreads lanes over all 8 bank-quads (8 lanes/quad = wave64 optimum).
// part stays linear (fold reads swizzled, writes linear).

__device__ __forceinline__ float4 f4add(float4 a, float4 b) {
    return make_float4(a.x + b.x, a.y + b.y, a.z + b.z, a.w + b.w);
}
__device__ __forceinline__ int swz(int f4) { return f4 ^ ((f4 >> 3) & 7); }

template<int PASS0>
__global__ __launch_bounds__(512, 4)   // 4 waves/EU -> 2 blocks/CU, VGPR<=128
void pass_kernel(const float* __restrict__ x,    // [64][2048][8]
                 const float* __restrict__ W,    // [2048][32][8][16]
                 const float* __restrict__ vin,  // [64][512] e-layout (o-major)
                 float* __restrict__ part)       // [64][256][512] e-layout
{
    __shared__ __align__(16) float x_lds[32 * 64];   //  8 KB: [bl][il*8+d]
    __shared__ __align__(16) float red[8 * 2 * 512]; // 32 KB: [w*2+bq][swz f4]
    __shared__ __align__(16) float vg[2 * 512];      //  4 KB: [bq][swz f4]

    const int t  = threadIdx.x;
    const int w  = t >> 6;
    const int l  = t & 63;
    const int o  = l & 31;
    const int kk = l >> 5;
    const int bx = blockIdx.x;
    const int ch = bx & 255;
    const int h  = bx >> 8;          // b-half: b in [h*32, h*32+32)
    const int i  = ch * 8 + w;

    // this lane's two float4 slots within a 128-f4 (512-float) e-row
    const int f4a = swz(o * 4 + kk * 2);
    const int f4b = swz(o * 4 + kk * 2 + 1);

    // ---- W[i][o][d][kk-half] -> 64 registers, PINNED so the compiler cannot
    // sink/rematerialize the loads into the g-loop.
    float Wr[8][8];
    {
        const float* wp = W + (size_t)(i * 32 + o) * 128 + kk * 8;
        #pragma unroll
        for (int d = 0; d < 8; ++d) {
            float4 a = *(const float4*)(wp + d * 16);
            float4 b = *(const float4*)(wp + d * 16 + 4);
            Wr[d][0] = a.x; Wr[d][1] = a.y; Wr[d][2] = a.z; Wr[d][3] = a.w;
            Wr[d][4] = b.x; Wr[d][5] = b.y; Wr[d][6] = b.z; Wr[d][7] = b.w;
        }
        #pragma unroll
        for (int d = 0; d < 8; ++d)
            #pragma unroll
            for (int j = 0; j < 8; ++j)
                asm volatile("" : "+v"(Wr[d][j]));   // force VGPR residency
    }
    // ---- stage x[h-half, chunk, :]: 2048 floats, one float4/thread ---------
    {
        const int f  = t * 4;
        const int bl = f >> 6, r = f & 63;
        *(float4*)&x_lds[f] =
            *(const float4*)(x + (size_t)(h * 32 + bl) * 16384 + ch * 64 + r);
    }

    for (int g = 0; g < 16; ++g) {       // 2 b's per group
        if (!PASS0) {
            if (t < 256) {               // stage vsum for the group's 2 b's
                const int bq = t >> 7, idx = t & 127;
                const int b  = h * 32 + g * 2 + bq;
                *(float4*)&vg[(bq * 128 + swz(idx)) * 4] =
                    *(const float4*)(vin + (size_t)b * 512 + idx * 4);
            }
        }
        __syncthreads();                 // vg ready (and x_lds/red safe)

        #pragma unroll
        for (int bq = 0; bq < 2; ++bq) {
            const int bl = g * 2 + bq;
            float4 xa = *(const float4*)&x_lds[bl * 64 + w * 8];
            float4 xb = *(const float4*)&x_lds[bl * 64 + w * 8 + 4];
            float xr[8] = {xa.x, xa.y, xa.z, xa.w, xb.x, xb.y, xb.z, xb.w};
            float uh[8];
            #pragma unroll
            for (int j = 0; j < 8; ++j) uh[j] = 0.f;
            #pragma unroll
            for (int d = 0; d < 8; ++d) {
                #pragma unroll
                for (int j = 0; j < 8; ++j)
                    uh[j] = fmaf(xr[d], Wr[d][j], uh[j]);
            }
            float c;
            if (PASS0) {
                c = 0.03125f;            // softmax of zeros
            } else {
                const float4 va = *(const float4*)&vg[(bq * 128 + f4a) * 4];
                const float4 vb = *(const float4*)&vg[(bq * 128 + f4b) * 4];
                float logit = uh[0] * va.x;
                logit = fmaf(uh[1], va.y, logit);
                logit = fmaf(uh[2], va.z, logit);
                logit = fmaf(uh[3], va.w, logit);
                logit = fmaf(uh[4], vb.x, logit);
                logit = fmaf(uh[5], vb.y, logit);
                logit = fmaf(uh[6], vb.z, logit);
                logit = fmaf(uh[7], vb.w, logit);
                logit += __shfl_xor(logit, 32, 64);   // combine k-halves
                float ex = __expf(logit);             // |logit| small: no max
                float sm = ex;
                #pragma unroll
                for (int off = 16; off >= 1; off >>= 1)
                    sm += __shfl_xor(sm, off, 64);    // denom over 32 o's
                c = __fdividef(ex, sm);
            }
            const int rb = (w * 2 + bq) * 128;
            *(float4*)&red[(rb + f4a) * 4] =
                make_float4(c * uh[0], c * uh[1], c * uh[2], c * uh[3]);
            *(float4*)&red[(rb + f4b) * 4] =
                make_float4(c * uh[4], c * uh[5], c * uh[6], c * uh[7]);
        }
        __syncthreads();                 // red complete

        if (t < 256) {                   // fold 8 i-slots -> per-chunk partial
            const int bq = t >> 7, j4 = t & 127;
            const int sj = swz(j4);
            float4 s = make_float4(0.f, 0.f, 0.f, 0.f);
            #pragma unroll
            for (int slot = 0; slot < 8; ++slot)
                s = f4add(s, *(const float4*)&red[((slot * 2 + bq) * 128 + sj) * 4]);
            const int b = h * 32 + g * 2 + bq;
            *(float4*)(part + ((size_t)b * 256 + ch) * 512 + j4 * 4) = s;   // linear
        }
        // no barrier needed: next group's first barrier orders red/vg reuse
    }
}

// ---------------------------------------------------------------------------
// Reduce: o-major e-layout lets every (b, 64-e slice) squash independently:
// grid 512 = (b = bx>>3) x (q = bx&7, e in [q*64, q*64+64)). 1024 threads:
// e = t&63, chunk-phase p = t>>6 (16 phases x 16 chunks each).
// PHASE 0: vsum=v; 1: vsum+=v; 2: out[b][o][k]=v (contiguous at e).
// ---------------------------------------------------------------------------
template<int PHASE>
__global__ __launch_bounds__(1024)
void reduce_kernel(const float* __restrict__ part,
                   float* __restrict__ vsum,
                   float* __restrict__ out)
{
    __shared__ float sred[16 * 64];
    const int bx = blockIdx.x;
    const int b  = bx >> 3;
    const int q  = bx & 7;
    const int t  = threadIdx.x;
    const int e  = t & 63;
    const int p  = t >> 6;

    const float* p0 = part + ((size_t)b * 256 + p) * 512 + q * 64 + e;
    float acc = 0.f;
    #pragma unroll
    for (int cc = 0; cc < 16; ++cc)            // ch = p + cc*16
        acc += p0[(size_t)cc * 16 * 512];
    sred[p * 64 + e] = acc;
    __syncthreads();

    if (t < 64) {                              // one wave finishes the slice
        float s = 0.f;
        #pragma unroll
        for (int pp = 0; pp < 16; ++pp)
            s += sred[pp * 64 + t];            // 2-way bank alias: free
        float sq = s * s;
        #pragma unroll
        for (int off = 8; off >= 1; off >>= 1)
            sq += __shfl_xor(sq, off, 16);     // sum over 16 k within o
        float v = (sq / (1.f + sq) * rsqrtf(sq + 1e-7f)) * s;
        const size_t idx = (size_t)b * 512 + q * 64 + t;
        if (PHASE == 2)      out[idx]   = v;   // e = o*16+k == out[b][o][k]
        else if (PHASE == 1) vsum[idx] += v;
        else                 vsum[idx]  = v;
    }
}

// ---------------------------------------------------------------------------
extern "C" void kernel_launch(void* const* d_in, const int* in_sizes, int n_in,
                              void* d_out, int out_size, void* d_ws, size_t ws_size,
                              hipStream_t stream)
{
    const float* x = (const float*)d_in[0];
    const float* W = (const float*)d_in[1];
    float* out = (float*)d_out;
    char* ws = (char*)d_ws;

    const size_t partB = (size_t)64 * 256 * 512 * 4;   // 32 MB
    const size_t vsumB = (size_t)64 * 512 * 4;         // 128 KB
    if (ws_size < partB + vsumB) return;               // ws ~33 MB: never taken

    float* part = (float*)ws;
    float* vsum = (float*)(ws + partB);

    // round 0: c uniform -> v0; vsum = v0
    pass_kernel<1><<<512, 512, 0, stream>>>(x, W, vsum, part);
    reduce_kernel<0><<<512, 1024, 0, stream>>>(part, vsum, out);
    // round 1: logits = u_hat . v0 -> v1; vsum = v0 + v1
    pass_kernel<0><<<512, 512, 0, stream>>>(x, W, vsum, part);
    reduce_kernel<1><<<512, 1024, 0, stream>>>(part, vsum, out);
    // round 2: logits = u_hat . (v0+v1) -> v2 = output
    pass_kernel<0><<<512, 512, 0, stream>>>(x, W, vsum, part);
    reduce_kernel<2><<<512, 1024, 0, stream>>>(part, vsum, out);
}

// Round 3
// 191.927 us; speedup vs baseline: 1.0746x; 1.0247x over previous
//
#include <hip/hip_runtime.h>

// B=64, I=2048, D=8, O=32, K=16.  e-layout o-major: e = o*16 + k.
//
// pass grid: 512 = (h = bx>>8: b-half) x (ch = bx&255: 8-i chunk).
// wave w = i-slot; lane: o = l&31, kk = l>>5. W[i][o][:][kk*8..+8] = 64 regs.
//
// Pipelined g-loop, ONE barrier per iter:
//   barrier; fold(g-1) from red[(g-1)&1]  ||  compute(g) -> red[g&1]
// red double-buffered (2x32KB). vg LDS deleted: with o-major e, a thread's 8
// v floats are contiguous in global (vin[b][o*16+kk*8]); 8 waves re-read the
// same 2KB/b -> L1-served. LDS total 72KB -> 2 blocks/CU.
//
// red float4 indices XOR-swizzled: swz(f4) = f4 ^ ((f4>>3)&7) (involution;
// spreads the o*4+kk*2 write pattern over all 8 bank-quads).

__device__ __forceinline__ float4 f4add(float4 a, float4 b) {
    return make_float4(a.x + b.x, a.y + b.y, a.z + b.z, a.w + b.w);
}
__device__ __forceinline__ int swz(int f4) { return f4 ^ ((f4 >> 3) & 7); }

template<int PASS0>
__global__ __launch_bounds__(512, 4)   // 128-reg budget, 2 blocks/CU
void pass_kernel(const float* __restrict__ x,    // [64][2048][8]
                 const float* __restrict__ W,    // [2048][32][8][16]
                 const float* __restrict__ vin,  // [64][512] e-layout (o-major)
                 float* __restrict__ part)       // [64][256][512] e-layout
{
    __shared__ __align__(16) float x_lds[32 * 64];     //  8 KB: [bl][il*8+d]
    __shared__ __align__(16) float red[2][16 * 512];   // 64 KB: [par][w*2+bq][swz]

    const int t  = threadIdx.x;
    const int w  = t >> 6;
    const int l  = t & 63;
    const int o  = l & 31;
    const int kk = l >> 5;
    const int bx = blockIdx.x;
    const int ch = bx & 255;
    const int h  = bx >> 8;          // b-half: b in [h*32, h*32+32)
    const int i  = ch * 8 + w;

    // this lane's two float4 slots within a 128-f4 (512-float) e-row
    const int f4a = swz(o * 4 + kk * 2);
    const int f4b = swz(o * 4 + kk * 2 + 1);
    // fold: all 512 threads, float2 granularity
    const int bqf = t >> 8;                  // which b of the pair
    const int j2  = t & 255;                 // float2 index in [0,256)
    const int sjf = swz(j2 >> 1) * 4 + (j2 & 1) * 2;   // swizzled float offset

    // ---- W[i][o][d][kk-half] -> 64 registers, PINNED (stops load sinking) --
    float Wr[8][8];
    {
        const float* wp = W + (size_t)(i * 32 + o) * 128 + kk * 8;
        #pragma unroll
        for (int d = 0; d < 8; ++d) {
            float4 a = *(const float4*)(wp + d * 16);
            float4 b = *(const float4*)(wp + d * 16 + 4);
            Wr[d][0] = a.x; Wr[d][1] = a.y; Wr[d][2] = a.z; Wr[d][3] = a.w;
            Wr[d][4] = b.x; Wr[d][5] = b.y; Wr[d][6] = b.z; Wr[d][7] = b.w;
        }
        #pragma unroll
        for (int d = 0; d < 8; ++d)
            #pragma unroll
            for (int j = 0; j < 8; ++j)
                asm volatile("" : "+v"(Wr[d][j]));
    }
    // ---- stage x[h-half, chunk, :]: 2048 floats, one float4/thread ---------
    {
        const int f  = t * 4;
        const int bl = f >> 6, r = f & 63;
        *(float4*)&x_lds[f] =
            *(const float4*)(x + (size_t)(h * 32 + bl) * 16384 + ch * 64 + r);
    }

    #pragma unroll 2
    for (int g = 0; g < 16; ++g) {       // 2 b's per group
        __syncthreads();                 // red[g&1] free; (g=0: x_lds ready)

        // ---- fold(g-1): sum 8 i-slots of red[(g-1)&1], write part ---------
        if (g) {
            const float* rp = red[(g - 1) & 1];
            float2 s = make_float2(0.f, 0.f);
            #pragma unroll
            for (int slot = 0; slot < 8; ++slot) {
                const float2 v = *(const float2*)&rp[(slot * 2 + bqf) * 512 + sjf];
                s.x += v.x; s.y += v.y;
            }
            const int b = h * 32 + (g - 1) * 2 + bqf;
            *(float2*)(part + ((size_t)b * 256 + ch) * 512 + j2 * 2) = s;
        }

        // ---- compute(g) -> red[g&1] ---------------------------------------
        float* rw = red[g & 1];
        #pragma unroll
        for (int bq = 0; bq < 2; ++bq) {
            const int bl = g * 2 + bq;
            float4 va, vb;
            if (!PASS0) {                // issue v loads first (L1/L2 latency)
                const float* vp = vin + (size_t)(h * 32 + bl) * 512 + o * 16 + kk * 8;
                va = *(const float4*)vp;
                vb = *(const float4*)(vp + 4);
            }
            float4 xa = *(const float4*)&x_lds[bl * 64 + w * 8];
            float4 xb = *(const float4*)&x_lds[bl * 64 + w * 8 + 4];
            float xr[8] = {xa.x, xa.y, xa.z, xa.w, xb.x, xb.y, xb.z, xb.w};
            float uh[8];
            #pragma unroll
            for (int j = 0; j < 8; ++j) uh[j] = 0.f;
            #pragma unroll
            for (int d = 0; d < 8; ++d) {
                #pragma unroll
                for (int j = 0; j < 8; ++j)
                    uh[j] = fmaf(xr[d], Wr[d][j], uh[j]);
            }
            float c;
            if (PASS0) {
                c = 0.03125f;            // softmax of zeros
            } else {
                float logit = uh[0] * va.x;
                logit = fmaf(uh[1], va.y, logit);
                logit = fmaf(uh[2], va.z, logit);
                logit = fmaf(uh[3], va.w, logit);
                logit = fmaf(uh[4], vb.x, logit);
                logit = fmaf(uh[5], vb.y, logit);
                logit = fmaf(uh[6], vb.z, logit);
                logit = fmaf(uh[7], vb.w, logit);
                logit += __shfl_xor(logit, 32, 64);   // combine k-halves
                float ex = __expf(logit);             // |logit| small: no max
                float sm = ex;
                #pragma unroll
                for (int off = 16; off >= 1; off >>= 1)
                    sm += __shfl_xor(sm, off, 64);    // denom over 32 o's
                c = __fdividef(ex, sm);
            }
            *(float4*)&rw[((w * 2 + bq) * 128 + f4a) * 4] =
                make_float4(c * uh[0], c * uh[1], c * uh[2], c * uh[3]);
            *(float4*)&rw[((w * 2 + bq) * 128 + f4b) * 4] =
                make_float4(c * uh[4], c * uh[5], c * uh[6], c * uh[7]);
        }
    }
    __syncthreads();
    {   // ---- epilogue fold(15) from red[1] --------------------------------
        const float* rp = red[1];
        float2 s = make_float2(0.f, 0.f);
        #pragma unroll
        for (int slot = 0; slot < 8; ++slot) {
            const float2 v = *(const float2*)&rp[(slot * 2 + bqf) * 512 + sjf];
            s.x += v.x; s.y += v.y;
        }
        const int b = h * 32 + 15 * 2 + bqf;
        *(float2*)(part + ((size_t)b * 256 + ch) * 512 + j2 * 2) = s;
    }
}

// ---------------------------------------------------------------------------
// Reduce: grid 512 = (b = bx>>3) x (q = bx&7: 64-e slice = 4 complete o's).
// 1024 threads: f = t&15 (float4 in slice), c0 = t>>4 (ch base); 4 float4
// loads/thread (256B quarter-wave segments), two-stage LDS fold, squash tail.
// PHASE 0: vsum=v; 1: vsum+=v; 2: out[b][o][k]=v (contiguous at e).
// ---------------------------------------------------------------------------
template<int PHASE>
__global__ __launch_bounds__(1024)
void reduce_kernel(const float* __restrict__ part,
                   float* __restrict__ vsum,
                   float* __restrict__ out)
{
    __shared__ __align__(16) float4 sred[64][16];   // 16 KB
    __shared__ __align__(16) float4 sredB[16][16];  //  4 KB
    const int bx = blockIdx.x;
    const int b  = bx >> 3;
    const int q  = bx & 7;
    const int t  = threadIdx.x;
    const int f  = t & 15;
    const int c0 = t >> 4;                          // ch base in [0,64)

    const float4* p4 =
        (const float4*)(part + ((size_t)b * 256 + c0) * 512 + q * 64) + f;
    // ch stride = 512 floats = 128 float4; cc adds 64 ch
    float4 s = f4add(f4add(p4[0],          p4[64 * 128]),
                     f4add(p4[128 * 128],  p4[192 * 128]));
    sred[c0][f] = s;
    __syncthreads();

    if (t < 256) {                                  // 64 -> 16 rows
        const int fr = t & 15, r = t >> 4;
        sredB[r][fr] = f4add(f4add(sred[r][fr],      sred[r + 16][fr]),
                             f4add(sred[r + 32][fr], sred[r + 48][fr]));
    }
    __syncthreads();

    if (t < 64) {                                   // one wave: 16 rows, squash
        const float* sB = (const float*)sredB;      // [16][64] floats
        float s1 = 0.f;
        #pragma unroll
        for (int r = 0; r < 16; ++r) s1 += sB[r * 64 + t];
        float sq = s1 * s1;
        #pragma unroll
        for (int off = 8; off >= 1; off >>= 1)
            sq += __shfl_xor(sq, off, 16);          // sum over 16 k within o
        float v = (sq / (1.f + sq) * rsqrtf(sq + 1e-7f)) * s1;
        const size_t idx = (size_t)b * 512 + q * 64 + t;
        if (PHASE == 2)      out[idx]   = v;        // e = o*16+k == [b][o][k]
        else if (PHASE == 1) vsum[idx] += v;
        else                 vsum[idx]  = v;
    }
}

// ---------------------------------------------------------------------------
extern "C" void kernel_launch(void* const* d_in, const int* in_sizes, int n_in,
                              void* d_out, int out_size, void* d_ws, size_t ws_size,
                              hipStream_t stream)
{
    const float* x = (const float*)d_in[0];
    const float* W = (const float*)d_in[1];
    float* out = (float*)d_out;
    char* ws = (char*)d_ws;

    const size_t partB = (size_t)64 * 256 * 512 * 4;   // 32 MB
    const size_t vsumB = (size_t)64 * 512 * 4;         // 128 KB
    if (ws_size < partB + vsumB) return;               // ws ~33 MB: never taken

    float* part = (float*)ws;
    float* vsum = (float*)(ws + partB);

    // round 0: c uniform -> v0; vsum = v0
    pass_kernel<1><<<512, 512, 0, stream>>>(x, W, vsum, part);
    reduce_kernel<0><<<512, 1024, 0, stream>>>(part, vsum, out);
    // round 1: logits = u_hat . v0 -> v1; vsum = v0 + v1
    pass_kernel<0><<<512, 512, 0, stream>>>(x, W, vsum, part);
    reduce_kernel<1><<<512, 1024, 0, stream>>>(part, vsum, out);
    // round 2: logits = u_hat . (v0+v1) -> v2 = output
    pass_kernel<0><<<512, 512, 0, stream>>>(x, W, vsum, part);
    reduce_kernel<2><<<512, 1024, 0, stream>>>(part, vsum, out);
}

// Round 4
// 181.311 us; speedup vs baseline: 1.1375x; 1.0586x over previous
//
#include <hip/hip_runtime.h>
#include <hip/hip_fp16.h>

// B=64, I=2048, D=8, O=32, K=16.  e-layout o-major: e = o*16 + k.
//
// pass grid: 512 = (h = bx>>8: b-half) x (ch = bx&255: 8-i chunk).
// wave w = i-slot; lane: o = l&31, kk = l>>5. W[i][o][:][kk*8..+8] = 64 regs.
//
// DS-pipe diet (round-3 postmortem: ~half of pass time was LDS/DS occupancy):
//  - softmax o-sum via DPP adds (VALU): quad_perm xor1/xor2 + row_ror 4/8,
//    then one ds_swizzle xor16; only 2 DS ops per bq (was 6 bpermutes).
//  - red + part stored as fp16 (accumulation stays f32): red write is one
//    ds_write_b128/bq, fold reads are b64, LDS 40KB, part traffic halved.
//    Precision: partials |v|~0.03, fp16 rounding -> abs err ~3e-4 on s.
// All red accesses lane-contiguous -> conflict-free, no swizzle needed.

struct __align__(16) H8 { __half2 a, b, c, d; };
struct __align__(8)  H4 { __half2 a, b; };

template<int CTRL>
__device__ __forceinline__ float dppadd(float x) {   // x + dpp_perm(x), VALU-only
    return x + __int_as_float(__builtin_amdgcn_update_dpp(
        0, __float_as_int(x), CTRL, 0xF, 0xF, true));
}

template<int PASS0>
__global__ __launch_bounds__(512, 4)   // 128-reg budget, 2 blocks/CU
void pass_kernel(const float* __restrict__ x,    // [64][2048][8]
                 const float* __restrict__ W,    // [2048][32][8][16]
                 const float* __restrict__ vin,  // [64][512] f32, o-major
                 __half* __restrict__ part)      // [64][256][512] fp16
{
    __shared__ __align__(16) float  x_lds[32 * 64];    //  8 KB: [bl][il*8+d]
    __shared__ __align__(16) __half redh[2][16][512];  // 32 KB: [par][slot*2+bq][e]

    const int t  = threadIdx.x;
    const int w  = t >> 6;
    const int l  = t & 63;
    const int o  = l & 31;
    const int kk = l >> 5;
    const int bx = blockIdx.x;
    const int ch = bx & 255;
    const int h  = bx >> 8;          // b-half: b in [h*32, h*32+32)
    const int i  = ch * 8 + w;

    // ---- W[i][o][d][kk-half] -> 64 registers, PINNED (stops load sinking) --
    float Wr[8][8];
    {
        const float* wp = W + (size_t)(i * 32 + o) * 128 + kk * 8;
        #pragma unroll
        for (int d = 0; d < 8; ++d) {
            float4 a = *(const float4*)(wp + d * 16);
            float4 b = *(const float4*)(wp + d * 16 + 4);
            Wr[d][0] = a.x; Wr[d][1] = a.y; Wr[d][2] = a.z; Wr[d][3] = a.w;
            Wr[d][4] = b.x; Wr[d][5] = b.y; Wr[d][6] = b.z; Wr[d][7] = b.w;
        }
        #pragma unroll
        for (int d = 0; d < 8; ++d)
            #pragma unroll
            for (int j = 0; j < 8; ++j)
                asm volatile("" : "+v"(Wr[d][j]));
    }
    // ---- stage x[h-half, chunk, :]: 2048 floats, one float4/thread ---------
    {
        const int f  = t * 4;
        const int bl = f >> 6, r = f & 63;
        *(float4*)&x_lds[f] =
            *(const float4*)(x + (size_t)(h * 32 + bl) * 16384 + ch * 64 + r);
    }

    #pragma unroll 2
    for (int g = 0; g < 16; ++g) {       // 2 b's per group
        __syncthreads();                 // red[g&1] free; (g=0: x_lds ready)

        // ---- fold(g-1): sum 8 i-slots of redh[(g-1)&1], write part (fp16) --
        if (g && t < 256) {
            const int bqf = t >> 7;
            const int hx  = (t & 127) * 4;           // half index in [0,512)
            const __half* rp = &redh[(g - 1) & 1][0][0];
            float a0 = 0.f, a1 = 0.f, a2 = 0.f, a3 = 0.f;
            #pragma unroll
            for (int s = 0; s < 8; ++s) {
                H4 v = *(const H4*)(rp + (s * 2 + bqf) * 512 + hx);
                float2 f0 = __half22float2(v.a), f1 = __half22float2(v.b);
                a0 += f0.x; a1 += f0.y; a2 += f1.x; a3 += f1.y;
            }
            const int b = h * 32 + (g - 1) * 2 + bqf;
            H4 o4;
            o4.a = __floats2half2_rn(a0, a1);
            o4.b = __floats2half2_rn(a2, a3);
            *(H4*)(part + ((size_t)b * 256 + ch) * 512 + hx) = o4;
        }

        // ---- compute(g) -> redh[g&1] --------------------------------------
        #pragma unroll
        for (int bq = 0; bq < 2; ++bq) {
            const int bl = g * 2 + bq;
            float4 va, vb;
            if (!PASS0) {                // issue v loads first (L1/L2 latency)
                const float* vp = vin + (size_t)(h * 32 + bl) * 512 + o * 16 + kk * 8;
                va = *(const float4*)vp;
                vb = *(const float4*)(vp + 4);
            }
            float4 xa = *(const float4*)&x_lds[bl * 64 + w * 8];   // broadcast
            float4 xb = *(const float4*)&x_lds[bl * 64 + w * 8 + 4];
            float xr[8] = {xa.x, xa.y, xa.z, xa.w, xb.x, xb.y, xb.z, xb.w};
            float uh[8];
            #pragma unroll
            for (int j = 0; j < 8; ++j) uh[j] = 0.f;
            #pragma unroll
            for (int d = 0; d < 8; ++d) {
                #pragma unroll
                for (int j = 0; j < 8; ++j)
                    uh[j] = fmaf(xr[d], Wr[d][j], uh[j]);
            }
            float c;
            if (PASS0) {
                c = 0.03125f;            // softmax of zeros
            } else {
                float logit = uh[0] * va.x;
                logit = fmaf(uh[1], va.y, logit);
                logit = fmaf(uh[2], va.z, logit);
                logit = fmaf(uh[3], va.w, logit);
                logit = fmaf(uh[4], vb.x, logit);
                logit = fmaf(uh[5], vb.y, logit);
                logit = fmaf(uh[6], vb.z, logit);
                logit = fmaf(uh[7], vb.w, logit);
                logit += __shfl_xor(logit, 32, 64);   // combine k-halves (1 DS)
                float ex = __expf(logit);             // |logit| small: no max
                // denom over 32 o's: 4 DPP adds (VALU) + 1 ds_swizzle xor16
                float sm = ex;
                sm = dppadd<0xB1>(sm);                // quad_perm xor1
                sm = dppadd<0x4E>(sm);                // quad_perm xor2
                sm = dppadd<0x124>(sm);               // row_ror:4
                sm = dppadd<0x128>(sm);               // row_ror:8 -> row sums
                sm += __int_as_float(__builtin_amdgcn_ds_swizzle(
                          __float_as_int(sm), 0x401F));   // xor16 within 32
                c = __fdividef(ex, sm);
            }
            H8 pk;
            pk.a = __floats2half2_rn(c * uh[0], c * uh[1]);
            pk.b = __floats2half2_rn(c * uh[2], c * uh[3]);
            pk.c = __floats2half2_rn(c * uh[4], c * uh[5]);
            pk.d = __floats2half2_rn(c * uh[6], c * uh[7]);
            *(H8*)&redh[g & 1][w * 2 + bq][o * 16 + kk * 8] = pk;   // 1 b128
        }
    }
    __syncthreads();
    if (t < 256) {   // ---- epilogue fold(15) from redh[1] -------------------
        const int bqf = t >> 7;
        const int hx  = (t & 127) * 4;
        const __half* rp = &redh[1][0][0];
        float a0 = 0.f, a1 = 0.f, a2 = 0.f, a3 = 0.f;
        #pragma unroll
        for (int s = 0; s < 8; ++s) {
            H4 v = *(const H4*)(rp + (s * 2 + bqf) * 512 + hx);
            float2 f0 = __half22float2(v.a), f1 = __half22float2(v.b);
            a0 += f0.x; a1 += f0.y; a2 += f1.x; a3 += f1.y;
        }
        const int b = h * 32 + 15 * 2 + bqf;
        H4 o4;
        o4.a = __floats2half2_rn(a0, a1);
        o4.b = __floats2half2_rn(a2, a3);
        *(H4*)(part + ((size_t)b * 256 + ch) * 512 + hx) = o4;
    }
}

// ---------------------------------------------------------------------------
// Reduce: grid 512 = (b = bx>>3) x (q = bx&7: 64-e slice = 4 complete o's).
// 1024 threads: f = t&7 (16B = 8 halves), c0 = t>>3 (chunk row in [0,128));
// 2 x 16B loads/thread (rows c0, c0+128), f32 accumulate, 3-stage LDS fold,
// squash tail. PHASE 0: vsum=v; 1: vsum+=v; 2: out[b][o][k]=v.
// ---------------------------------------------------------------------------
template<int PHASE>
__global__ __launch_bounds__(1024)
void reduce_kernel(const __half* __restrict__ part,
                   float* __restrict__ vsum,
                   float* __restrict__ out)
{
    __shared__ __align__(16) float sA[128][64];   // 32 KB
    __shared__ __align__(16) float sB[16][64];    //  4 KB
    const int bx = blockIdx.x;
    const int b  = bx >> 3;
    const int q  = bx & 7;
    const int t  = threadIdx.x;
    const int f  = t & 7;
    const int c0 = t >> 3;                        // chunk row in [0,128)

    const __half* p0 = part + ((size_t)b * 256 + c0) * 512 + q * 64 + f * 8;
    float acc[8] = {0.f, 0.f, 0.f, 0.f, 0.f, 0.f, 0.f, 0.f};
    #pragma unroll
    for (int rr = 0; rr < 2; ++rr) {              // rows c0, c0+128
        H8 v = *(const H8*)(p0 + (size_t)rr * 128 * 512);
        float2 f0 = __half22float2(v.a), f1 = __half22float2(v.b),
               f2 = __half22float2(v.c), f3 = __half22float2(v.d);
        acc[0] += f0.x; acc[1] += f0.y; acc[2] += f1.x; acc[3] += f1.y;
        acc[4] += f2.x; acc[5] += f2.y; acc[6] += f3.x; acc[7] += f3.y;
    }
    *(float4*)&sA[c0][f * 8]     = make_float4(acc[0], acc[1], acc[2], acc[3]);
    *(float4*)&sA[c0][f * 8 + 4] = make_float4(acc[4], acc[5], acc[6], acc[7]);
    __syncthreads();

    {                                             // 128 rows -> 16
        const int e = t & 63, r4 = t >> 6;        // r4 in [0,16)
        float sb = 0.f;
        #pragma unroll
        for (int k2 = 0; k2 < 8; ++k2) sb += sA[r4 + k2 * 16][e];
        sB[r4][e] = sb;
    }
    __syncthreads();

    if (t < 64) {                                 // one wave: 16 rows, squash
        float s1 = 0.f;
        #pragma unroll
        for (int r = 0; r < 16; ++r) s1 += sB[r][t];
        float sq = s1 * s1;
        #pragma unroll
        for (int off = 8; off >= 1; off >>= 1)
            sq += __shfl_xor(sq, off, 16);        // sum over 16 k within o
        float v = (sq / (1.f + sq) * rsqrtf(sq + 1e-7f)) * s1;
        const size_t idx = (size_t)b * 512 + q * 64 + t;
        if (PHASE == 2)      out[idx]   = v;      // e = o*16+k == [b][o][k]
        else if (PHASE == 1) vsum[idx] += v;
        else                 vsum[idx]  = v;
    }
}

// ---------------------------------------------------------------------------
extern "C" void kernel_launch(void* const* d_in, const int* in_sizes, int n_in,
                              void* d_out, int out_size, void* d_ws, size_t ws_size,
                              hipStream_t stream)
{
    const float* x = (const float*)d_in[0];
    const float* W = (const float*)d_in[1];
    float* out = (float*)d_out;
    char* ws = (char*)d_ws;

    const size_t partB = (size_t)64 * 256 * 512 * 2;   // 16 MB (fp16)
    const size_t vsumB = (size_t)64 * 512 * 4;         // 128 KB
    if (ws_size < partB + vsumB) return;               // never taken

    __half* part = (__half*)ws;
    float*  vsum = (float*)(ws + partB);

    // round 0: c uniform -> v0; vsum = v0
    pass_kernel<1><<<512, 512, 0, stream>>>(x, W, vsum, part);
    reduce_kernel<0><<<512, 1024, 0, stream>>>(part, vsum, out);
    // round 1: logits = u_hat . v0 -> v1; vsum = v0 + v1
    pass_kernel<0><<<512, 512, 0, stream>>>(x, W, vsum, part);
    reduce_kernel<1><<<512, 1024, 0, stream>>>(part, vsum, out);
    // round 2: logits = u_hat . (v0+v1) -> v2 = output
    pass_kernel<0><<<512, 512, 0, stream>>>(x, W, vsum, part);
    reduce_kernel<2><<<512, 1024, 0, stream>>>(part, vsum, out);
}